// Round 1
// baseline (57.768 us; speedup 1.0000x reference)
//
#include <hip/hip_runtime.h>

// Reference collapse: softmax over a size-1 axis == 1.0, so the q/x path is
// dead. out[b,c,h,w] = y[b,c] where
//   v[b,i] = sum_j context[b,j]*Wv[i,j]
//   y[b,c] = sum_i Wo[c,i]*v[b,i] + bo[c]

#define CONTEXT_DIM 16
#define INNER 512
#define NB 2
#define OUT_C 256
#define HW 65536   // 256*256

// ---------------- kernel 1: tiny prologue, one block of 512 threads --------
__global__ __launch_bounds__(512) void compute_y_kernel(
        const float* __restrict__ context,   // [2][16]
        const float* __restrict__ Wv,        // [512][16]
        const float* __restrict__ Wo,        // [256][512]
        const float* __restrict__ bo,        // [256]
        float* __restrict__ y)               // [2][256] out
{
    __shared__ float v_s[NB][INNER];
    const int t = threadIdx.x;               // 0..511

    // phase 1: v[b][t] = context[b,:] . Wv[t,:]   (coalesced-ish, tiny)
    #pragma unroll
    for (int b = 0; b < NB; ++b) {
        float acc = 0.f;
        #pragma unroll
        for (int j = 0; j < CONTEXT_DIM; ++j)
            acc += context[b * CONTEXT_DIM + j] * Wv[t * CONTEXT_DIM + j];
        v_s[b][t] = acc;
    }
    __syncthreads();

    // phase 2: thread t -> (b = t>>8, c = t&255): y = Wo[c,:] . v[b,:] + bo[c]
    const int b = t >> 8;
    const int c = t & 255;
    const float* __restrict__ wrow = Wo + (size_t)c * INNER;
    float acc = bo[c];
    #pragma unroll 8
    for (int i = 0; i < INNER; ++i)
        acc += wrow[i] * v_s[b][i];
    y[t] = acc;                              // y[b*256 + c]
}

// ---------------- kernel 2: broadcast write, float4 stores -----------------
// One block fills 1/4 of a (b,c) plane: 16384 floats = 64 KB.
// grid = 512 planes * 4 = 2048 blocks, 256 threads.
__global__ __launch_bounds__(256) void broadcast_kernel(
        const float* __restrict__ y,         // [512]
        float4* __restrict__ out)            // [2*256][HW/4] as float4
{
    const int bc      = blockIdx.x >> 2;
    const int quarter = blockIdx.x & 3;
    const float val = y[bc];                 // broadcast load (L2-resident)
    const float4 v4 = make_float4(val, val, val, val);

    float4* __restrict__ base =
        out + (size_t)bc * (HW / 4) + (size_t)quarter * (HW / 16);
    const int t = threadIdx.x;
    #pragma unroll
    for (int it = 0; it < 16; ++it)          // 16 * 256 * 16B = 64 KB
        base[it * 256 + t] = v4;
}

extern "C" void kernel_launch(void* const* d_in, const int* in_sizes, int n_in,
                              void* d_out, int out_size, void* d_ws, size_t ws_size,
                              hipStream_t stream) {
    // setup_inputs order: x, context, Wq, Wk, Wv, Wo, bo  (all fp32)
    const float* context = (const float*)d_in[1];
    const float* Wv      = (const float*)d_in[4];
    const float* Wo      = (const float*)d_in[5];
    const float* bo      = (const float*)d_in[6];
    float* out = (float*)d_out;
    float* y   = (float*)d_ws;               // 512 floats of scratch

    compute_y_kernel<<<1, 512, 0, stream>>>(context, Wv, Wo, bo, y);
    broadcast_kernel<<<NB * OUT_C * 4, 256, 0, stream>>>(y, (float4*)out);
}

// Round 2
// 44.193 us; speedup vs baseline: 1.3072x; 1.3072x over previous
//
#include <hip/hip_runtime.h>

// Reference collapse: softmax over a size-1 axis == 1.0, so the q/x path is
// dead. out[b,c,h,w] = y[b,c] where
//   v[b,i] = sum_j context[b,j]*Wv[i,j]
//   y[b,c] = sum_i Wo[c,i]*v[b,i] + bo[c]
//
// Single fused kernel: each block owns one quarter of one (b,c) plane
// (16384 floats = 64 KB). Each WAVE redundantly computes the scalar y[b,c]
// (8 i-values per lane -> 64-lane butterfly reduce; no LDS, no syncthreads),
// then the block streams its 64 KB with coalesced float4 stores. Wv (32 KB)
// and Wo (512 KB) are L2-resident after the first blocks, so HBM traffic is
// essentially the 134 MB of output writes.

#define CONTEXT_DIM 16
#define INNER 512
#define NB 2
#define OUT_C 256
#define HW 65536   // 256*256

__global__ __launch_bounds__(256) void fused_value_broadcast_kernel(
        const float* __restrict__ context,   // [2][16]
        const float* __restrict__ Wv,        // [512][16]
        const float* __restrict__ Wo,        // [256][512]
        const float* __restrict__ bo,        // [256]
        float4* __restrict__ out)            // [512][HW/4] as float4
{
    const int bc      = blockIdx.x >> 2;     // 0..511  (b*256 + c)
    const int quarter = blockIdx.x & 3;
    const int b       = bc >> 8;
    const int c       = bc & 255;

    const int lane = threadIdx.x & 63;

    // ---- per-wave redundant computation of y[b,c] ----
    // lane handles i = lane*8 .. lane*8+7 (contiguous rows of Wv)
    float ctx[CONTEXT_DIM];
    #pragma unroll
    for (int j = 0; j < CONTEXT_DIM; ++j)
        ctx[j] = context[b * CONTEXT_DIM + j];

    const float* __restrict__ wvrow = Wv + (size_t)(lane * 8) * CONTEXT_DIM;
    const float* __restrict__ worow = Wo + (size_t)c * INNER + lane * 8;

    float acc = 0.f;
    #pragma unroll
    for (int k = 0; k < 8; ++k) {
        // v[b, lane*8+k] = ctx . Wv[lane*8+k, :]   (row is 64 B, float4-aligned)
        const float4* wv4 = (const float4*)(wvrow + k * CONTEXT_DIM);
        float v = 0.f;
        #pragma unroll
        for (int j4 = 0; j4 < CONTEXT_DIM / 4; ++j4) {
            float4 w = wv4[j4];
            v += ctx[j4 * 4 + 0] * w.x + ctx[j4 * 4 + 1] * w.y
               + ctx[j4 * 4 + 2] * w.z + ctx[j4 * 4 + 3] * w.w;
        }
        acc += worow[k] * v;
    }
    // 64-lane butterfly reduce: every lane ends with the full sum
    #pragma unroll
    for (int off = 32; off >= 1; off >>= 1)
        acc += __shfl_xor(acc, off, 64);

    const float val = acc + bo[c];
    const float4 v4 = make_float4(val, val, val, val);

    // ---- stream 64 KB: 16 iterations x 256 threads x 16 B, coalesced ----
    float4* __restrict__ base =
        out + (size_t)bc * (HW / 4) + (size_t)quarter * (HW / 16);
    const int t = threadIdx.x;
    #pragma unroll
    for (int it = 0; it < 16; ++it)
        base[it * 256 + t] = v4;
}

extern "C" void kernel_launch(void* const* d_in, const int* in_sizes, int n_in,
                              void* d_out, int out_size, void* d_ws, size_t ws_size,
                              hipStream_t stream) {
    // setup_inputs order: x, context, Wq, Wk, Wv, Wo, bo  (all fp32)
    const float* context = (const float*)d_in[1];
    const float* Wv      = (const float*)d_in[4];
    const float* Wo      = (const float*)d_in[5];
    const float* bo      = (const float*)d_in[6];

    fused_value_broadcast_kernel<<<NB * OUT_C * 4, 256, 0, stream>>>(
        context, Wv, Wo, bo, (float4*)d_out);
}

// Round 4
// 28.924 us; speedup vs baseline: 1.9972x; 1.5279x over previous
//
#include <hip/hip_runtime.h>

// Reference collapse: softmax over a size-1 axis == 1.0, so the q/x path is
// dead. out[b,c,h,w] = y[b,c] where
//   v[b,i] = sum_j context[b,j]*Wv[i,j]
//   y[b,c] = sum_i Wo[c,i]*v[b,i] + bo[c]
//
// One block per (b,c) plane: 512 blocks x 1024 threads (= 2 blocks/CU).
// Waves 0..3 cooperatively compute the scalar y[b,c] (each lane: 2 Wv rows,
// 2 Wo weights), one LDS combine + barrier, then all 16 waves stream the
// 256 KB plane with coalesced nontemporal float4 stores.

#define CONTEXT_DIM 16
#define INNER 512
#define NB 2
#define OUT_C 256
#define HW 65536   // 256*256

// native vector type: __builtin_nontemporal_store rejects HIP_vector_type
typedef float f4 __attribute__((ext_vector_type(4)));

__global__ __launch_bounds__(1024) void fused_value_broadcast_kernel(
        const float* __restrict__ context,   // [2][16]
        const float* __restrict__ Wv,        // [512][16]
        const float* __restrict__ Wo,        // [256][512]
        const float* __restrict__ bo,        // [256]
        f4* __restrict__ out)                // [512][HW/4] as f4
{
    const int bc = blockIdx.x;               // 0..511  (b*256 + c)
    const int b  = bc >> 8;
    const int c  = bc & 255;

    const int t    = threadIdx.x;            // 0..1023
    const int w    = t >> 6;                 // wave id 0..15
    const int lane = t & 63;

    __shared__ float part[4];

    if (w < 4) {
        // context row is block-uniform -> scalar loads
        float ctx[CONTEXT_DIM];
        #pragma unroll
        for (int j = 0; j < CONTEXT_DIM; ++j)
            ctx[j] = context[b * CONTEXT_DIM + j];

        // this wave covers i in [w*128, w*128+128); lane handles 2 rows
        const int i0 = w * 128 + lane * 2;
        const f4* __restrict__ wv4 =
            (const f4*)(Wv + (size_t)i0 * CONTEXT_DIM);
        const float2 wo2 =
            *(const float2*)(Wo + (size_t)c * INNER + i0);

        float acc = 0.f;
        #pragma unroll
        for (int r = 0; r < 2; ++r) {
            float v = 0.f;
            #pragma unroll
            for (int j4 = 0; j4 < CONTEXT_DIM / 4; ++j4) {
                f4 wv = wv4[r * (CONTEXT_DIM / 4) + j4];
                v += ctx[j4 * 4 + 0] * wv.x + ctx[j4 * 4 + 1] * wv.y
                   + ctx[j4 * 4 + 2] * wv.z + ctx[j4 * 4 + 3] * wv.w;
            }
            acc += (r == 0 ? wo2.x : wo2.y) * v;
        }
        // wave reduce -> lane 0
        #pragma unroll
        for (int off = 32; off >= 1; off >>= 1)
            acc += __shfl_xor(acc, off, 64);
        if (lane == 0) part[w] = acc;
    }
    __syncthreads();

    const float val = part[0] + part[1] + part[2] + part[3] + bo[c];
    f4 v4;
    v4.x = val; v4.y = val; v4.z = val; v4.w = val;

    // stream the full plane: 16 iters x 1024 threads x 16 B = 256 KB
    f4* __restrict__ base = out + (size_t)bc * (HW / 4);
    #pragma unroll
    for (int it = 0; it < 16; ++it)
        __builtin_nontemporal_store(v4, &base[it * 1024 + t]);
}

extern "C" void kernel_launch(void* const* d_in, const int* in_sizes, int n_in,
                              void* d_out, int out_size, void* d_ws, size_t ws_size,
                              hipStream_t stream) {
    // setup_inputs order: x, context, Wq, Wk, Wv, Wo, bo  (all fp32)
    const float* context = (const float*)d_in[1];
    const float* Wv      = (const float*)d_in[4];
    const float* Wo      = (const float*)d_in[5];
    const float* bo      = (const float*)d_in[6];

    fused_value_broadcast_kernel<<<NB * OUT_C, 1024, 0, stream>>>(
        context, Wv, Wo, bo, (f4*)d_out);
}

// Round 5
// 26.820 us; speedup vs baseline: 2.1539x; 1.0784x over previous
//
#include <hip/hip_runtime.h>

// Reference collapse: softmax over a size-1 axis == 1.0, so the q/x path is
// dead. out[b,c,h,w] = y[b,c] where
//   v[b,i] = sum_j context[b,j]*Wv[i,j]
//   y[b,c] = sum_i Wo[c,i]*v[b,i] + bo[c]
//
// One block per (b,c) plane: 512 blocks x 1024 threads (= 2 blocks/CU, max
// occupancy). All 16 waves cooperate on the scalar y[b,c]: thread t covers
// half of Wv row i = t>>1 (32 B), multiplies by Wo[c,i]; wave butterfly +
// LDS combine, one barrier, then all 16 waves stream the 256 KB plane with
// plain coalesced dwordx4 stores (matches the 7 TB/s fillBuffer path --
// nontemporal removed as the R4->R5 A/B variable).

#define CONTEXT_DIM 16
#define INNER 512
#define NB 2
#define OUT_C 256
#define HW 65536   // 256*256

typedef float f4 __attribute__((ext_vector_type(4)));

__global__ __launch_bounds__(1024) void fused_value_broadcast_kernel(
        const float* __restrict__ context,   // [2][16]
        const float* __restrict__ Wv,        // [512][16]
        const float* __restrict__ Wo,        // [256][512]
        const float* __restrict__ bo,        // [256]
        f4* __restrict__ out)                // [512][HW/4] as f4
{
    const int bc = blockIdx.x;               // 0..511  (b*256 + c)
    const int b  = bc >> 8;
    const int c  = bc & 255;

    const int t    = threadIdx.x;            // 0..1023
    const int w    = t >> 6;                 // wave id 0..15
    const int lane = t & 63;

    __shared__ float part[16];

    // ---- cooperative prologue: all 16 waves ----
    // thread t handles row i = t>>1, half h = t&1 (8 of 16 j's, 32 B).
    {
        const int i = t >> 1;
        const int h = t & 1;

        // 8 block-uniform context scalars for this half
        const float* __restrict__ ctxp = context + b * CONTEXT_DIM + h * 8;
        const f4* __restrict__ wv4 =
            (const f4*)(Wv + (size_t)i * CONTEXT_DIM + h * 8);

        f4 wv0 = wv4[0], wv1 = wv4[1];
        float v = ctxp[0] * wv0.x + ctxp[1] * wv0.y
                + ctxp[2] * wv0.z + ctxp[3] * wv0.w
                + ctxp[4] * wv1.x + ctxp[5] * wv1.y
                + ctxp[6] * wv1.z + ctxp[7] * wv1.w;
        float acc = v * Wo[(size_t)c * INNER + i];

        #pragma unroll
        for (int off = 32; off >= 1; off >>= 1)
            acc += __shfl_xor(acc, off, 64);
        if (lane == 0) part[w] = acc;
    }
    __syncthreads();

    float val = bo[c];
    #pragma unroll
    for (int k = 0; k < 16; ++k) val += part[k];

    f4 v4;
    v4.x = val; v4.y = val; v4.z = val; v4.w = val;

    // ---- stream the full plane: 16 iters x 1024 threads x 16 B = 256 KB ----
    f4* __restrict__ base = out + (size_t)bc * (HW / 4);
    #pragma unroll
    for (int it = 0; it < 16; ++it)
        base[it * 1024 + t] = v4;
}

extern "C" void kernel_launch(void* const* d_in, const int* in_sizes, int n_in,
                              void* d_out, int out_size, void* d_ws, size_t ws_size,
                              hipStream_t stream) {
    // setup_inputs order: x, context, Wq, Wk, Wv, Wo, bo  (all fp32)
    const float* context = (const float*)d_in[1];
    const float* Wv      = (const float*)d_in[4];
    const float* Wo      = (const float*)d_in[5];
    const float* bo      = (const float*)d_in[6];

    fused_value_broadcast_kernel<<<NB * OUT_C, 1024, 0, stream>>>(
        context, Wv, Wo, bo, (f4*)d_out);
}